// Round 6
// baseline (367.711 us; speedup 1.0000x reference)
//
#include <hip/hip_runtime.h>
#include <hip/hip_bf16.h>

// HMLSTMCell2: B=65536, H=128, gates = 513-wide GEMM (K=384) + pointwise epilogue.
// Gate columns 0..511 via bf16 MFMA 16x16x32; column 512 (sz -> hard threshold z_new)
// in fp64 on the exact scaled fp32 A values.
// R9 = hybrid of the two proven halves (R4 96us > R6 118 > R8 179):
//  - W path from R4: bf16 pre-swizzled Wt in d_ws, global_load_lds (width 16) into
//    a double-buffered 32 KB LDS chunk shared by all 8 waves; ONE barrier/chunk;
//    staging latency rides under the MFMA cluster, drained by vmcnt(0) just before
//    the barrier (issued ~350 cy earlier).
//  - A path from R8: each lane loads its own 2 rows x 8 k fp32 directly to regs,
//    scales by z/zb (exact {0,1}), converts via v_cvt_pk_bf16_f32 (RNE = f2bf).
//    NO ldsA: the A chain (HBM load -> VALU -> pack) is register-private and OFF
//    the barrier critical path (R4's main stall).
//  - sz fp64 on the two ws==0 waves, reduced with shfl_xor (no ldsSZ).
// Per-chunk barrier interval ~= MFMA-pipe floor (64 MFMA x ~19.4 cy/SIMD at 4
// waves/SIMD); 2 independent blocks/CU (LDS 67 KB, target <=64 arch VGPR) drift
// and cover each other's waits.

#define MT   64          // rows per block
#define BK   32          // K chunk
#define NKC  12          // 384 / 32
#define NT   512         // threads per block (8 waves)
#define COFF 8388608     // c_new offset in d_out (65536*128)
#define ZOFF 16777216    // z_new offset (2*65536*128)

using short8 = __attribute__((ext_vector_type(8))) short;  // 8 bf16 (4 VGPR)
using f32x4  = __attribute__((ext_vector_type(4))) float;  // MFMA acc frag

__device__ __forceinline__ unsigned short f2bf(float f) {
  union { float f; unsigned u; } v; v.f = f;
  unsigned r = (v.u + 0x7FFFu + ((v.u >> 16) & 1u)) >> 16;  // RNE truncate
  return (unsigned short)r;
}

__device__ __forceinline__ unsigned cvt_pk_bf16(float lo, float hi) {
  unsigned r;                       // dst[15:0]=bf16(lo), dst[31:16]=bf16(hi), RNE
  asm("v_cvt_pk_bf16_f32 %0, %1, %2" : "=v"(r) : "v"(lo), "v"(hi));
  return r;
}

__device__ __forceinline__ void async_copy16(const void* g, void* l) {
  __builtin_amdgcn_global_load_lds(
      (const __attribute__((address_space(1))) unsigned int*)g,
      (__attribute__((address_space(3))) unsigned int*)l, 16, 0, 0);
}

__device__ __forceinline__ float sigm(float x)     { return 1.f / (1.f + __expf(-x)); }
__device__ __forceinline__ float tanh_fast(float x){ return 1.f - 2.f / (1.f + __expf(2.f * x)); }

// d_ws layout (R4-proven): bf16, element ((c*512 + n)*4 + (u ^ ((n>>1)&3)))*8 + j
// holds Wc[k = c*32 + u*8 + j][n], Wc = [W; R; U] (cols 0..511). XOR pre-swizzle
// pairs with the linear global_load_lds copy + swizzled ds_read (2 lanes/bank,
// free per m136; measured 8K conflicts total in R4).
__global__ void prep_weights(const float* __restrict__ W, const float* __restrict__ R,
                             const float* __restrict__ U, unsigned short* __restrict__ Wt) {
  int idx = blockIdx.x * blockDim.x + threadIdx.x;   // 0 .. 24575
  if (idx >= NKC * 512 * 4) return;
  int up = idx & 3;            // physical 16B unit within row
  int n  = (idx >> 2) & 511;   // output column
  int c  = idx >> 11;          // K chunk
  int ul = up ^ ((n >> 1) & 3);// logical unit
  int k0 = c * 32 + ul * 8;    // global k of first element
  const float* src; int kb;
  if (k0 < 128)      { src = W; kb = 0;   }
  else if (k0 < 256) { src = R; kb = 128; }
  else               { src = U; kb = 256; }
  const float* colp = src + (size_t)(k0 - kb) * 513 + n;
  unsigned short vs[8];
  #pragma unroll
  for (int j = 0; j < 8; ++j) vs[j] = f2bf(colp[j * 513]);
  uint4 o;
  o.x = (unsigned)vs[0] | ((unsigned)vs[1] << 16);
  o.y = (unsigned)vs[2] | ((unsigned)vs[3] << 16);
  o.z = (unsigned)vs[4] | ((unsigned)vs[5] << 16);
  o.w = (unsigned)vs[6] | ((unsigned)vs[7] << 16);
  reinterpret_cast<uint4*>(Wt)[idx] = o;
}

__global__ __launch_bounds__(NT, 4)
void hmlstm_main(const float* __restrict__ hb, const float* __restrict__ hs,
                 const float* __restrict__ ht, const float* __restrict__ cs,
                 const float* __restrict__ zp, const float* __restrict__ zbp,
                 const float* __restrict__ W,  const float* __restrict__ R,
                 const float* __restrict__ U,  const float* __restrict__ b,
                 const unsigned short* __restrict__ Wt, float* __restrict__ out)
{
  __shared__ unsigned short ldsW[2][512 * BK];   // 64 KB, double-buffered W chunks
  __shared__ float ldsWL[384];                   // fp32 col-512 weights (sz path)
  // total 67072 B -> 2 blocks/CU by LDS

  const int tid  = threadIdx.x;
  const int l    = tid & 63;
  const int wv   = tid >> 6;   // 0..7
  const int ws   = wv & 3;     // 32-H-col slice
  const int wr   = wv >> 2;    // row half (32 rows)
  const int q    = l >> 4;     // quad 0..3 = k-unit
  const int lr   = l & 15;
  const int row0 = blockIdx.x * MT;

  for (int k = tid; k < 384; k += NT) {
    ldsWL[k] = (k < 128) ? W[k * 513 + 512]
             : (k < 256) ? R[(k - 128) * 513 + 512]
                         : U[(k - 256) * 513 + 512];
  }

  // A rows this lane feeds to MFMA: A-operand row = lane&15 (+16 for second frag)
  const int r0 = row0 + wr * 32 + lr;
  const int r1 = r0 + 16;
  const float zb0 = zbp[r0], zb1 = zbp[r1];      // all exactly 0.0 or 1.0
  const float zv0 = zp[r0],  zv1 = zp[r1];

  f32x4 acc[2][8];                               // [row 16-group][gate*2+half], 64 AGPR
  {
    f32x4 zf = {0.f, 0.f, 0.f, 0.f};
    #pragma unroll
    for (int i = 0; i < 2; ++i)
      #pragma unroll
      for (int j = 0; j < 8; ++j) acc[i][j] = zf;
  }

  double sz0 = 0.0, sz1 = 0.0;
  const bool szw = (ws == 0);                    // 2 of 8 waves own the sz path

  const unsigned a0off = (unsigned)r0 * 128 + q * 8;   // float index
  const unsigned a1off = (unsigned)r1 * 128 + q * 8;

  f32x4 av[4];                                   // in-flight fp32 A (single buffer)
  short8 af0, af1;                               // current bf16 A fragments

  auto loadA = [&](int c) {
    const float* s = (c < 4) ? hb : (c < 8) ? hs : ht;
    const unsigned ko = (unsigned)(c & 3) * 32;
    av[0] = *(const f32x4*)(s + a0off + ko);
    av[1] = *(const f32x4*)(s + a0off + ko + 4);
    av[2] = *(const f32x4*)(s + a1off + ko);
    av[3] = *(const f32x4*)(s + a1off + ko + 4);
  };
  auto cvtA = [&](int c) {
    f32x4 v0 = av[0], v1 = av[1], v2 = av[2], v3 = av[3];
    if (c < 4)       { v0 *= zb0; v1 *= zb0; v2 *= zb1; v3 *= zb1; }
    else if (c >= 8) { v0 *= zv0; v1 *= zv0; v2 *= zv1; v3 *= zv1; }
    if (szw) {                                   // sz: fp64 dot on exact scaled fp32
      const float* wl = ldsWL + c * 32 + q * 8;  // broadcast reads (uniform per q)
      f32x4 w0 = *(const f32x4*)wl;
      f32x4 w1 = *(const f32x4*)(wl + 4);
      sz0 += (double)v0.x * w0.x + (double)v0.y * w0.y + (double)v0.z * w0.z + (double)v0.w * w0.w
           + (double)v1.x * w1.x + (double)v1.y * w1.y + (double)v1.z * w1.z + (double)v1.w * w1.w;
      sz1 += (double)v2.x * w0.x + (double)v2.y * w0.y + (double)v2.z * w0.z + (double)v2.w * w0.w
           + (double)v3.x * w1.x + (double)v3.y * w1.y + (double)v3.z * w1.z + (double)v3.w * w1.w;
    }
    union { unsigned u[4]; short8 s8; } pk0, pk1;
    pk0.u[0] = cvt_pk_bf16(v0.x, v0.y); pk0.u[1] = cvt_pk_bf16(v0.z, v0.w);
    pk0.u[2] = cvt_pk_bf16(v1.x, v1.y); pk0.u[3] = cvt_pk_bf16(v1.z, v1.w);
    pk1.u[0] = cvt_pk_bf16(v2.x, v2.y); pk1.u[1] = cvt_pk_bf16(v2.z, v2.w);
    pk1.u[2] = cvt_pk_bf16(v3.x, v3.y); pk1.u[3] = cvt_pk_bf16(v3.z, v3.w);
    af0 = pk0.s8; af1 = pk1.s8;
  };
  auto stageW = [&](int c, int buf) {
    const unsigned short* gW = Wt + c * (512 * BK);
    #pragma unroll
    for (int r = 0; r < 4; ++r) {
      int eo = (wv * 4 + r) * 512;               // 8 waves x 4 rounds x 512 shorts
      async_copy16(gW + eo + l * 8, &ldsW[buf][eo]);  // lane -> base + lane*16B
    }
  };

  // ---- prologue ----
  loadA(0);                                      // private A(0) in flight
  stageW(0, 0);                                  // W(0) -> LDS, in flight
  asm volatile("s_waitcnt lgkmcnt(0)" ::: "memory");  // ldsWL writes (this wave)
  __builtin_amdgcn_s_barrier();                  // ldsWL visible to all
  cvtA(0);                                       // waits A(0) via compiler vmcnt
  asm volatile("s_waitcnt vmcnt(0)" ::: "memory");    // W(0) landed in LDS
  __builtin_amdgcn_s_barrier();                  // release ldsW[0] readers

  // ---- main loop: one barrier/chunk; A private, W amortized via LDS ----
  #pragma unroll 1
  for (int kc = 0; kc < NKC; ++kc) {
    const int cur = kc & 1;
    if (kc < NKC - 1) {
      loadA(kc + 1);                             // 4 vmem (oldest: deadline = cvtA)
      stageW(kc + 1, cur ^ 1);                   // 4 global_load_lds (deadline = barrier)
    }
    #pragma unroll
    for (int tn = 0; tn < 8; ++tn) {             // 8 ds_read_b128 + 16 MFMA
      int nc = (tn >> 1) * 128 + ws * 32 + (tn & 1) * 16 + lr;  // gate-spread cols
      short8 bf = *(const short8*)&ldsW[cur][nc * BK + ((q ^ ((nc >> 1) & 3)) * 8)];
      acc[0][tn] = __builtin_amdgcn_mfma_f32_16x16x32_bf16(af0, bf, acc[0][tn], 0, 0, 0);
      acc[1][tn] = __builtin_amdgcn_mfma_f32_16x16x32_bf16(af1, bf, acc[1][tn], 0, 0, 0);
    }
    if (kc < NKC - 1) {
      cvtA(kc + 1);                              // compiler waits vmcnt(4): A done,
                                                 // stageW stays in flight
      asm volatile("s_waitcnt vmcnt(0)" ::: "memory");   // stageW landed (covered
                                                         // by MFMA cluster above)
      asm volatile("s_waitcnt lgkmcnt(0)" ::: "memory"); // ds_reads of cur done
      __builtin_amdgcn_s_barrier();
    }
  }

  // ---- z_new: q-slice fp64 partials -> shfl_xor reduce, threshold sz > 0 ----
  if (szw) {
    sz0 += __shfl_xor(sz0, 16); sz0 += __shfl_xor(sz0, 32);
    sz1 += __shfl_xor(sz1, 16); sz1 += __shfl_xor(sz1, 32);
    if (l < 16) {
      const float bz = b[512];
      out[ZOFF + r0] = ((float)sz0 + bz > 0.f) ? 1.f : 0.f;
      out[ZOFF + r1] = ((float)sz1 + bz > 0.f) ? 1.f : 0.f;
    }
  }

  // ---- epilogue: wave owns 32 rows x 32 cols; each 128 B out-line written whole ----
  float bias[2][4];
  #pragma unroll
  for (int th = 0; th < 2; ++th) {
    const int col = ws * 32 + th * 16 + lr;
    bias[th][0] = b[col];       bias[th][1] = b[128 + col];
    bias[th][2] = b[256 + col]; bias[th][3] = b[384 + col];
  }
  #pragma unroll
  for (int s = 0; s < 2; ++s) {
    #pragma unroll
    for (int r = 0; r < 4; ++r) {
      const int row = row0 + wr * 32 + s * 16 + q * 4 + r;  // C/D: row = quad*4 + reg
      const float zr  = zp[row];
      const float zbr = zbp[row];
      const size_t rowoff = (size_t)row * 128;
      #pragma unroll
      for (int th = 0; th < 2; ++th) {
        const int col = ws * 32 + th * 16 + lr;             // C/D: col = lane&15
        const size_t off = rowoff + col;
        float si = acc[s][0 + th][r] + bias[th][0];
        float sg = acc[s][2 + th][r] + bias[th][1];
        float so = acc[s][4 + th][r] + bias[th][2];
        float sf = acc[s][6 + th][r] + bias[th][3];
        float iv = sigm(si);
        float gv = tanh_fast(sg);
        float ov = sigm(so);
        float fv = sigm(sf);
        float ig = iv * gv;
        float cv = 0.f, hv = 0.f;
        if (zr != 1.f) cv = cs[off];               // row-uniform guard, whole lines
        const bool keep = (zr == 0.f) && (zbr == 0.f);
        if (keep) hv = hs[off];
        float cn = (zr == 1.f) ? ig : ((zbr == 0.f) ? cv : cv * fv + ig);
        float hn = keep ? hv : tanh_fast(cn) * ov;
        out[off]        = hn;
        out[COFF + off] = cn;
      }
    }
  }
}

extern "C" void kernel_launch(void* const* d_in, const int* in_sizes, int n_in,
                              void* d_out, int out_size, void* d_ws, size_t ws_size,
                              hipStream_t stream) {
  const float* hb  = (const float*)d_in[0];
  const float* hs  = (const float*)d_in[1];
  const float* ht  = (const float*)d_in[2];
  const float* cs  = (const float*)d_in[3];
  const float* zp  = (const float*)d_in[4];
  const float* zbp = (const float*)d_in[5];
  const float* W   = (const float*)d_in[6];
  const float* R   = (const float*)d_in[7];
  const float* U   = (const float*)d_in[8];
  const float* b   = (const float*)d_in[9];
  unsigned short* Wt = (unsigned short*)d_ws;   // 12*512*32*2 = 393216 B
  float* out = (float*)d_out;

  prep_weights<<<dim3(96), dim3(256), 0, stream>>>(W, R, U, Wt);
  hmlstm_main<<<dim3(65536 / MT), dim3(NT), 0, stream>>>(
      hb, hs, ht, cs, zp, zbp, W, R, U, b, Wt, out);
}

// Round 7
// 247.221 us; speedup vs baseline: 1.4874x; 1.4874x over previous
//
#include <hip/hip_runtime.h>
#include <hip/hip_bf16.h>

// HMLSTMCell2: B=65536, H=128, gates = 513-wide GEMM (K=384) + pointwise epilogue.
// Gate columns 0..511 via bf16 MFMA 16x16x32; column 512 (sz -> hard threshold z_new)
// in fp64 fused into A staging. Weights pre-converted to bf16 in d_ws
// (wave-fragment blocked, frag stride 1024 B) and read straight to registers.
// R9->R10: R9's WRITE 351MB was SCRATCH (spill: private-A needs ~84 arch regs vs
// the 64 cap of launch_bounds(512,4); R8 proved demand=84). Revert to R6's
// proven dataflow (A via LDS staging = low reg demand, compiled exactly 64+64;
// W reg-direct; ONE lgkm-only barrier/chunk) and attack the REAL common
// bottleneck: R4/R6 ran only 2 independent 8-wave barrier groups per CU, so
// every intra-group serialization idled the pipes (interval 9600cy vs 1240
// MFMA floor, MfmaUtil 10.7%). Re-cut to NT=256 / MT=32: 4 waves per block
// (one per SIMD), 4 blocks/CU = 4 drifting barrier groups, occupancy 50%.
// Wave output tile stays 32 rows x 128 gate-cols -> whole-128B-line writes.
// f2bf packs replaced by v_cvt_pk_bf16_f32 (RNE-identical, ~20 fewer VALU
// ops/thread/chunk, fewer live temps).

#define MT   32          // rows per block
#define BK   32          // K chunk
#define NKC  12          // 384 / 32
#define NT   256         // threads per block (4 waves)
#define COFF 8388608     // c_new offset in d_out (65536*128)
#define ZOFF 16777216    // z_new offset (2*65536*128)

using short8 = __attribute__((ext_vector_type(8))) short;  // 8 bf16 (4 VGPR)
using f32x4  = __attribute__((ext_vector_type(4))) float;  // MFMA acc frag

__device__ __forceinline__ unsigned short f2bf(float f) {
  union { float f; unsigned u; } v; v.f = f;
  unsigned r = (v.u + 0x7FFFu + ((v.u >> 16) & 1u)) >> 16;  // RNE truncate
  return (unsigned short)r;
}

__device__ __forceinline__ unsigned cvt_pk_bf16(float lo, float hi) {
  unsigned r;                       // dst[15:0]=bf16(lo), dst[31:16]=bf16(hi), RNE
  asm("v_cvt_pk_bf16_f32 %0, %1, %2" : "=v"(r) : "v"(lo), "v"(hi));
  return r;
}

__device__ __forceinline__ float sigm(float x)     { return 1.f / (1.f + __expf(-x)); }
__device__ __forceinline__ float tanh_fast(float x){ return 1.f - 2.f / (1.f + __expf(2.f * x)); }

// d_ws layout (wave-fragment blocked, R6-proven): short index
//   ((((c*4 + s)*8 + tn)*16 + x)*4 + u)*8 + j
// holds Wc[k = c*32 + u*8 + j][n],  n = (tn>>1)*128 + s*32 + (tn&1)*16 + x,
// Wc = [W; R; U] (cols 0..511). Wave with col-slice s reads frag tn of chunk c
// at byte (c*32768 + s*8192 + tn*1024 + lr*64 + q*16): 1 KB contiguous per load.
__global__ void prep_weights(const float* __restrict__ W, const float* __restrict__ R,
                             const float* __restrict__ U, unsigned short* __restrict__ Wt) {
  int idx = blockIdx.x * blockDim.x + threadIdx.x;   // 0 .. 24575, one 16B unit each
  if (idx >= NKC * 512 * 4) return;
  int u  = idx & 3;            // k unit within chunk
  int x  = (idx >> 2) & 15;    // col within 16-slice
  int tn = (idx >> 6) & 7;     // frag: gate = tn>>1, half = tn&1
  int s  = (idx >> 9) & 3;     // wave col-slice
  int c  = idx >> 11;          // K chunk
  int n  = (tn >> 1) * 128 + s * 32 + (tn & 1) * 16 + x;  // gemm column
  int k0 = c * 32 + u * 8;     // global k of first element
  const float* src; int kb;
  if (k0 < 128)      { src = W; kb = 0;   }
  else if (k0 < 256) { src = R; kb = 128; }
  else               { src = U; kb = 256; }
  const float* colp = src + (size_t)(k0 - kb) * 513 + n;
  unsigned short vs[8];
  #pragma unroll
  for (int j = 0; j < 8; ++j) vs[j] = f2bf(colp[j * 513]);
  uint4 o;
  o.x = (unsigned)vs[0] | ((unsigned)vs[1] << 16);
  o.y = (unsigned)vs[2] | ((unsigned)vs[3] << 16);
  o.z = (unsigned)vs[4] | ((unsigned)vs[5] << 16);
  o.w = (unsigned)vs[6] | ((unsigned)vs[7] << 16);
  reinterpret_cast<uint4*>(Wt)[idx] = o;
}

__global__ __launch_bounds__(NT, 4)
void hmlstm_main(const float* __restrict__ hb, const float* __restrict__ hs,
                 const float* __restrict__ ht, const float* __restrict__ cs,
                 const float* __restrict__ zp, const float* __restrict__ zbp,
                 const float* __restrict__ W,  const float* __restrict__ R,
                 const float* __restrict__ U,  const float* __restrict__ b,
                 const unsigned short* __restrict__ Wt, float* __restrict__ out)
{
  __shared__ unsigned short ldsA[2][MT * BK];    // 4 KB, double-buffered A chunks
  __shared__ float  ldsWL[384];                  // fp32 col-512 weights (sz path)
  __shared__ double ldsSZ[NT];                   // sz partial reduce (fp64)
  // total 7680 B -> LDS irrelevant; occupancy set by regs (128/wave -> 4/SIMD)

  const int tid  = threadIdx.x;
  const int l    = tid & 63;
  const int wv   = tid >> 6;   // 0..3 = col-slice (one wave per SIMD)
  const int q    = l >> 4;     // quad 0..3 = k-unit
  const int lr   = l & 15;
  const int row0 = blockIdx.x * MT;

  for (int k = tid; k < 384; k += NT) {
    ldsWL[k] = (k < 128) ? W[k * 513 + 512]
             : (k < 256) ? R[(k - 128) * 513 + 512]
                         : U[(k - 256) * 513 + 512];
  }

  // A-staging assignment: thread -> (row m, 4-float group p); fixed across chunks
  const int m    = tid >> 3;       // 0..31
  const int p    = tid & 7;        // 0..7
  const int arow = row0 + m;
  const float zbv = zbp[arow];
  const float zv  = zp[arow];
  double szacc = 0.0;

  f32x4 acc[2][8];                 // [row 16-group][gate*2+half], 64 AGPRs
  {
    f32x4 zf = {0.f, 0.f, 0.f, 0.f};
    #pragma unroll
    for (int i = 0; i < 2; ++i)
      #pragma unroll
      for (int j = 0; j < 8; ++j) acc[i][j] = zf;
  }

  // swizzled 8B half-slot for A staging (16B-unit XOR matches the read side;
  // spreads ds_read_b128 start banks 2 lanes/bank = free per m136)
  const int aW = m * BK + (((p >> 1) ^ ((m >> 1) & 3)) * 8) + (p & 1) * 4;
  const size_t rowb = (size_t)arow * 128 + p * 4;

  auto loadA = [&](int c) -> f32x4 {
    const float* src = (c < 4) ? hb : (c < 8) ? hs : ht;
    return *(const f32x4*)(src + rowb + (c & 3) * 32);
  };
  auto consumeA = [&](int c, f32x4 v, int buf) {
    const float scale = (c < 4) ? zbv : (c < 8) ? 1.f : zv;
    v *= scale;
    const float* wl = ldsWL + c * 32 + p * 4;
    szacc += (double)v.x * wl[0] + (double)v.y * wl[1]
           + (double)v.z * wl[2] + (double)v.w * wl[3];
    uint2 pk;
    pk.x = cvt_pk_bf16(v.x, v.y);
    pk.y = cvt_pk_bf16(v.z, v.w);
    *(uint2*)&ldsA[buf][aW] = pk;
  };

  // per-lane W fragment pointer: chunk stride 16384 shorts (32 KB), frag stride
  // 512 shorts (1024 B, imm-foldable); covers cols (tn>>1)*128 + wv*32 + (tn&1)*16 + lr
  const unsigned short* wkc = Wt + (size_t)wv * 4096 + lr * 32 + q * 8;

  // ---- prologue ----
  f32x4 a0 = loadA(0);
  short8 wf[8];
  #pragma unroll
  for (int tn = 0; tn < 8; ++tn)
    wf[tn] = *(const short8*)(wkc + tn * 512);     // chunk 0 B-frags in flight
  asm volatile("s_waitcnt lgkmcnt(0)" ::: "memory");
  __builtin_amdgcn_s_barrier();                    // ldsWL visible
  consumeA(0, a0, 0);                              // waits vmcnt for a0 only
  f32x4 ain = loadA(1);
  asm volatile("s_waitcnt lgkmcnt(0)" ::: "memory");
  __builtin_amdgcn_s_barrier();                    // ldsA[0] visible

  // ---- main loop: one lgkm-only barrier/chunk; W rides register prefetch ----
  #pragma unroll 1
  for (int kc = 0; kc < NKC; ++kc) {
    const int cur = kc & 1;
    short8 af[2];
    #pragma unroll
    for (int s = 0; s < 2; ++s) {
      int mr = s * 16 + lr;                        // A[m = lane&15][k = q*8+j]
      af[s] = *(const short8*)&ldsA[cur][mr * BK + ((q ^ ((mr >> 1) & 3)) * 8)];
    }
    #pragma unroll
    for (int tn = 0; tn < 8; ++tn) {               // waits vmcnt for wf; ain stays
      acc[0][tn] = __builtin_amdgcn_mfma_f32_16x16x32_bf16(af[0], wf[tn], acc[0][tn], 0, 0, 0);
      acc[1][tn] = __builtin_amdgcn_mfma_f32_16x16x32_bf16(af[1], wf[tn], acc[1][tn], 0, 0, 0);
    }
    if (kc < NKC - 1) {
      #pragma unroll
      for (int tn = 0; tn < 8; ++tn)               // next chunk B-frags (WAR on wf
        wf[tn] = *(const short8*)(wkc + (kc + 1) * 16384 + tn * 512);  // after MFMA)
      consumeA(kc + 1, ain, cur ^ 1);              // stage next A (scale/sz/pack)
      if (kc < NKC - 2) ain = loadA(kc + 2);
      asm volatile("s_waitcnt lgkmcnt(0)" ::: "memory");  // A writes+reads drained
      __builtin_amdgcn_s_barrier();
    }
  }

  // ---- z_new: fp64 sz reduce (8 partials per row), hard threshold sz > 0 ----
  ldsSZ[tid] = szacc;
  __syncthreads();
  if (tid < MT) {
    const double* pz = &ldsSZ[tid * 8];
    double ss = ((pz[0] + pz[1]) + (pz[2] + pz[3])) + ((pz[4] + pz[5]) + (pz[6] + pz[7]));
    float s = (float)ss + b[512];
    out[ZOFF + row0 + tid] = (s > 0.f) ? 1.f : 0.f;
  }

  // ---- epilogue: wave owns 32 rows x 32 cols; each 128 B out-line written whole ----
  float bias[2][4];
  #pragma unroll
  for (int th = 0; th < 2; ++th) {
    const int col = wv * 32 + th * 16 + lr;
    bias[th][0] = b[col];       bias[th][1] = b[128 + col];
    bias[th][2] = b[256 + col]; bias[th][3] = b[384 + col];
  }
  #pragma unroll
  for (int s = 0; s < 2; ++s) {
    #pragma unroll
    for (int r = 0; r < 4; ++r) {
      const int row = row0 + s * 16 + q * 4 + r;   // C/D: row = quad*4 + reg
      const float zr  = zp[row];
      const float zbr = zbp[row];
      const size_t rowoff = (size_t)row * 128;
      #pragma unroll
      for (int th = 0; th < 2; ++th) {
        const int col = wv * 32 + th * 16 + lr;    // C/D: col = lane&15
        const size_t off = rowoff + col;
        float si = acc[s][0 + th][r] + bias[th][0];
        float sg = acc[s][2 + th][r] + bias[th][1];
        float so = acc[s][4 + th][r] + bias[th][2];
        float sf = acc[s][6 + th][r] + bias[th][3];
        float iv = sigm(si);
        float gv = tanh_fast(sg);
        float ov = sigm(so);
        float fv = sigm(sf);
        float ig = iv * gv;
        float cv = 0.f, hv = 0.f;
        if (zr != 1.f) cv = cs[off];               // row-uniform guard, whole lines
        const bool keep = (zr == 0.f) && (zbr == 0.f);
        if (keep) hv = hs[off];
        float cn = (zr == 1.f) ? ig : ((zbr == 0.f) ? cv : cv * fv + ig);
        float hn = keep ? hv : tanh_fast(cn) * ov;
        out[off]        = hn;
        out[COFF + off] = cn;
      }
    }
  }
}

extern "C" void kernel_launch(void* const* d_in, const int* in_sizes, int n_in,
                              void* d_out, int out_size, void* d_ws, size_t ws_size,
                              hipStream_t stream) {
  const float* hb  = (const float*)d_in[0];
  const float* hs  = (const float*)d_in[1];
  const float* ht  = (const float*)d_in[2];
  const float* cs  = (const float*)d_in[3];
  const float* zp  = (const float*)d_in[4];
  const float* zbp = (const float*)d_in[5];
  const float* W   = (const float*)d_in[6];
  const float* R   = (const float*)d_in[7];
  const float* U   = (const float*)d_in[8];
  const float* b   = (const float*)d_in[9];
  unsigned short* Wt = (unsigned short*)d_ws;   // 12*512*32*2 = 393216 B
  float* out = (float*)d_out;

  prep_weights<<<dim3(96), dim3(256), 0, stream>>>(W, R, U, Wt);
  hmlstm_main<<<dim3(65536 / MT), dim3(NT), 0, stream>>>(
      hb, hs, ht, cs, zp, zbp, W, R, U, b, Wt, out);
}